// Round 17
// baseline (555.607 us; speedup 1.0000x reference)
//
#include <hip/hip_runtime.h>

typedef __attribute__((ext_vector_type(4))) float f4;
typedef __attribute__((ext_vector_type(8))) short s16x8;
typedef __attribute__((ext_vector_type(4))) unsigned short us4;
typedef __attribute__((ext_vector_type(2))) unsigned int u32x2;
typedef unsigned short u16;
typedef unsigned int u32;

#define DEVI __device__ __forceinline__

DEVI u16 f2bf(float f){
    u32 u = __builtin_bit_cast(u32, f);
    u32 r = (u + 0x7fffu + ((u >> 16) & 1u)) >> 16;
    return (u16)r;
}
DEVI float bf2f(u16 h){
    u32 u = ((u32)h) << 16;
    return __builtin_bit_cast(float, u);
}
DEVI f4 mfma16(s16x8 a, s16x8 b, f4 c){
    return __builtin_amdgcn_mfma_f32_16x16x32_bf16(a, b, c, 0, 0, 0);
}
DEVI u32 cvtpk(float lo, float hi){
    u32 r;
    asm("v_cvt_pk_bf16_f32 %0, %1, %2" : "=v"(r) : "v"(lo), "v"(hi));
    return r;
}
// async global->LDS, 16B per lane; dst = wave-uniform base + lane*16
DEVI void gload(const u16* g, u16* l){
    __builtin_amdgcn_global_load_lds((const __attribute__((address_space(1))) void*)g,
                                     (__attribute__((address_space(3))) void*)l, 16, 0, 0);
}

#define L2E 1.44269504088896340736f

// ---------------- weight bf16 cast ----------------
__global__ __launch_bounds__(256) void k_cast(const float* w2, const float* wqk,
                                              const float* wv, const float* wt,
                                              const float* wf, u16* out){
    int i = blockIdx.x * 256 + threadIdx.x;
    if(i < 16384)       out[i] = f2bf(w2[i]);
    else if(i < 32768)  out[i] = f2bf(wqk[i - 16384]);
    else if(i < 98304)  out[i] = f2bf(wv[i - 32768]);
    else if(i < 163840) out[i] = f2bf(wt[i - 98304]);
    else if(i < 688128){
        int t = i - 163840;          // t = o*512 + c
        int o = t >> 9, c = t & 511;
        int jg = o >> 4, l15 = o & 15, ks = c >> 5, kr = c & 31;
        out[163840 + (size_t)(jg*16 + ks)*512 + ((kr>>3)*16 + l15)*8 + (kr&7)] = f2bf(wf[t]);
    }
}

// ---------------- stem conv1 (+bn+relu) -> h1 bf16 n-major [b][n][128] ----------------
__global__ __launch_bounds__(256) void k_stem1(const float* x, const float* w1,
                                               const float* g1, const float* b1, u16* h1tb){
    int t = blockIdx.x * 256 + threadIdx.x;      // 16*2048
    int b = t >> 11, n = t & 2047;
    const float* xb = x + (size_t)b * 3 * 2048 + n;
    float x0 = xb[0], x1 = xb[2048], x2 = xb[4096];
    u32* o = (u32*)(h1tb + (size_t)t * 128);
    #pragma unroll 8
    for(int c = 0; c < 128; c += 2){
        float a0 = fmaxf(g1[c]   * (w1[c*3+0]*x0 + w1[c*3+1]*x1 + w1[c*3+2]*x2) + b1[c],   0.f);
        float a1 = fmaxf(g1[c+1] * (w1[c*3+3]*x0 + w1[c*3+4]*x1 + w1[c*3+5]*x2) + b1[c+1], 0.f);
        o[c >> 1] = (u32)f2bf(a0) | ((u32)f2bf(a1) << 16);
    }
}

// XCD swizzles: b -> fixed XCD, consistent across grids.
DEVI int swz512(int bid){ return ((bid & 7) << 6) | (bid >> 3); }
DEVI int swz1024(int bid){ return ((bid & 7) << 7) | (bid >> 3); }
DEVI int swz2048(int bid){ return ((bid & 7) << 8) | (bid >> 3); }

// ---------------- shared qv phase (A-tile in swizzled LDS), 4-wave version ----------------
DEVI void qv_phase(const u16* T, const u16* wqkb, const u16* wvb, const float* bv,
                   u16* qb, u16* vt, int b, int n0, int wv_, int l15, int kg){
    f4 accv[8], accq[2];
    #pragma unroll
    for(int j=0;j<8;j++) accv[j] = (f4){0.f,0.f,0.f,0.f};
    accq[0] = (f4){0.f,0.f,0.f,0.f}; accq[1] = accq[0];
    int row = wv_*16 + l15;
    #pragma unroll
    for(int ks=0; ks<4; ks++){
        s16x8 a = *(const s16x8*)&T[row*128 + ((ks*32 + kg*8) ^ ((row&7)<<3))];
        #pragma unroll
        for(int j=0;j<8;j++){
            s16x8 bb = *(const s16x8*)(wvb + (size_t)(j*16 + l15)*128 + ks*32 + kg*8);
            accv[j] = mfma16(a, bb, accv[j]);
        }
        #pragma unroll
        for(int f=0; f<2; f++){
            s16x8 wf_ = *(const s16x8*)(wqkb + (size_t)(f*16 + l15)*128 + ks*32 + kg*8);
            accq[f] = mfma16(wf_, a, accq[f]);
        }
    }
    int nb = n0 + wv_*16;
    int it = nb >> 5;
    int k0 = (nb & 31) + kg*4;
    int vbase = ((k0 >> 3)*16)*8 + (k0 & 7);
    #pragma unroll
    for(int j=0;j<8;j++){
        float bvo = bv[j*16 + l15];
        us4 pk;
        #pragma unroll
        for(int r=0;r<4;r++) pk[r] = f2bf(accv[j][r] + bvo);
        *(us4*)(vt + (size_t)((b*64 + it)*8 + j)*512 + vbase + l15*8) = pk;
    }
    int n = n0 + wv_*16 + l15;
    #pragma unroll
    for(int f=0; f<2; f++){
        us4 pk;
        #pragma unroll
        for(int r=0;r<4;r++) pk[r] = f2bf(accq[f][r]);
        *(us4*)(qb + (size_t)(b*2048 + n)*32 + f*16 + kg*4) = pk;
    }
}

// ---------------- conv2 (+bn+relu) + fused q/v projection (blk0); h kept bf16 only ----------------
__global__ __launch_bounds__(256) void k_conv2qv(const u16* h1tb, const u16* w2b,
                                                 const float* g2, const float* b2,
                                                 u16* htb,
                                                 const u16* wqkb, const u16* wvb,
                                                 const float* bv, u16* qb, u16* vt){
    __shared__ u16 T[8192];
    int bid2 = swz512(blockIdx.x);
    int b = bid2 >> 5;
    int n0 = (bid2 & 31) << 6;
    int lane = threadIdx.x & 63, wv_ = threadIdx.x >> 6;
    int l15 = lane & 15, kg = lane >> 4;
    const u16* arow = h1tb + (size_t)(b*2048 + n0 + wv_*16 + l15) * 128 + kg*8;
    f4 acc[8];
    #pragma unroll
    for(int j=0;j<8;j++) acc[j] = (f4){0.f,0.f,0.f,0.f};
    #pragma unroll
    for(int ks=0; ks<4; ks++){
        s16x8 a = *(const s16x8*)(arow + ks*32);
        #pragma unroll
        for(int j=0;j<8;j++){
            s16x8 bb = *(const s16x8*)(w2b + (size_t)(j*16 + l15)*128 + ks*32 + kg*8);
            acc[j] = mfma16(a, bb, acc[j]);
        }
    }
    int nn0 = n0 + wv_*16 + kg*4;
    #pragma unroll
    for(int j=0;j<8;j++){
        int o = j*16 + l15;
        float gg = g2[o], be = b2[o];
        #pragma unroll
        for(int r=0;r<4;r++){
            float h = fmaxf(gg * acc[j][r] + be, 0.f);
            int nl = wv_*16 + kg*4 + r;
            u16 hb = f2bf(h);
            htb[(size_t)(b*2048 + nn0 + r) * 128 + o] = hb;
            T[nl*128 + (o ^ ((nl&7)<<3))] = hb;
        }
    }
    __syncthreads();
    qv_phase(T, wqkb, wvb, bv, qb, vt, b, n0, wv_, l15, kg);
}

// ---------------- pass A (j quarters): crowp[jq][b][i] = log2(sum_j exp e) ----------------
// grid 2048 = 16b x 32 i-groups x 4 jq; 8 blocks/CU -> 32 waves/CU.
__global__ __launch_bounds__(256) void k_passA(const u16* qb, float* crowp){
    int bid2 = swz2048(blockIdx.x);
    int b = bid2 >> 7;
    int rest = bid2 & 127;
    int i0 = (rest >> 2) << 6;
    int jq = rest & 3;
    int jbeg = jq << 9;
    int lane = threadIdx.x & 63, wv_ = threadIdx.x >> 6;
    int l15 = lane & 15, kg = lane >> 4;
    const u16* qbase = qb + (size_t)b * 2048 * 32;
    s16x8 af = *(const s16x8*)(qbase + (size_t)(i0 + wv_*16 + l15)*32 + kg*8);
    float m[4], s[4], mml[4];
    const f4 z = {0.f,0.f,0.f,0.f};
    {
        s16x8 b0 = *(const s16x8*)(qbase + (size_t)(jbeg + l15)*32 + kg*8);
        s16x8 b1 = *(const s16x8*)(qbase + (size_t)(jbeg + 16 + l15)*32 + kg*8);
        f4 e0 = mfma16(af, b0, z);
        f4 e1 = mfma16(af, b1, z);
        #pragma unroll
        for(int r=0;r<4;r++){
            m[r] = fmaxf(e0[r], e1[r]);
            mml[r] = -m[r]*L2E;
            s[r] = exp2f(fmaf(e0[r], L2E, mml[r])) + exp2f(fmaf(e1[r], L2E, mml[r]));
        }
    }
    for(int j0=jbeg+32; j0<jbeg+512; j0+=32){
        s16x8 b0 = *(const s16x8*)(qbase + (size_t)(j0 + l15)*32 + kg*8);
        s16x8 b1 = *(const s16x8*)(qbase + (size_t)(j0 + 16 + l15)*32 + kg*8);
        f4 e0 = mfma16(af, b0, z);
        f4 e1 = mfma16(af, b1, z);
        #pragma unroll
        for(int r=0;r<4;r++){
            float mx = fmaxf(e0[r], e1[r]);
            if(mx > m[r] + 8.f){
                s[r] *= exp2f((m[r]-mx)*L2E);
                m[r] = mx; mml[r] = -mx*L2E;
            }
            s[r] += exp2f(fmaf(e0[r], L2E, mml[r])) + exp2f(fmaf(e1[r], L2E, mml[r]));
        }
    }
    #pragma unroll
    for(int d=1; d<16; d<<=1){
        #pragma unroll
        for(int r=0;r<4;r++){
            float mo = __shfl_xor(m[r], d);
            float so = __shfl_xor(s[r], d);
            float mn = fmaxf(m[r], mo);
            s[r] = s[r]*exp2f((m[r]-mn)*L2E) + so*exp2f((mo-mn)*L2E);
            m[r] = mn;
        }
    }
    if(l15 == 0){
        #pragma unroll
        for(int r=0;r<4;r++){
            int i = i0 + wv_*16 + kg*4 + r;
            crowp[jq*32768 + b*2048 + i] = m[r]*L2E + log2f(s[r]);
        }
    }
}

// ---------------- pass B + tail + next-qv fused (R14 config, bf16 residual) ----------------
// Phase 1 roles: 8 waves = (jw 0..1: 32 j) x (ih 0..1: i-half) x (jcH 0..1: c-half).
// Phase 2 roles: (wv>>1: 16 j, wv&1: o-half) reading shared Td.
// LDS: [0,32768) V dbuf | [32768,49152) P dbuf 2x8KB | [49152,57344) CR | [57344,58368) csl[4][64]
__global__ __launch_bounds__(512) void k_passBT(const u16* qb, const u16* vt,
                                                const float* crowp,
                                                const u16* hprev, int ldh,
                                                const u16* wtb, const float* bt,
                                                const float* sg, const float* sb,
                                                u16* catb_o,
                                                const u16* wqkb2, const u16* wvb2,
                                                const float* bv2,
                                                u16* qb2, u16* vt2, int doQV){
    __shared__ __align__(16) char SB[58368];
    u16*   V   = (u16*)SB;
    u16*   P   = (u16*)(SB + 32768);          // P[buf] = P + buf*4096 (u16)
    float* CR  = (float*)(SB + 49152);
    float* csl = (float*)(SB + 57344);        // [g 4][64]
    int bid2 = swz512(blockIdx.x);
    int b = bid2 >> 5;
    int j0 = (bid2 & 31) << 6;
    int tid = threadIdx.x;
    int lane = tid & 63, wv_ = tid >> 6;
    int jw = wv_ >> 2, ih = (wv_ >> 1) & 1, jcH = wv_ & 1;
    int l15 = lane & 15, kg = lane >> 4;
    int jh = jw * 32;
    int pairOff = (jw*2 + ih) * 1024;
    int isub = ih*2 + jcH;
    const u16* qbase = qb + (size_t)b * 2048 * 32;
    const u16* vtb = vt + (size_t)b * 64*8*512;

    // combine 4 log-domain quarters: CR = log2(sum 2^cq)
    #pragma unroll
    for(int p=0;p<4;p++){
        int i = p*512 + tid;
        float c0 = crowp[b*2048 + i],          c1 = crowp[32768 + b*2048 + i];
        float c2 = crowp[65536 + b*2048 + i],  c3 = crowp[98304 + b*2048 + i];
        float mx = fmaxf(fmaxf(c0, c1), fmaxf(c2, c3));
        float sum = exp2f(c0 - mx) + exp2f(c1 - mx) + exp2f(c2 - mx) + exp2f(c3 - mx);
        CR[i] = mx + log2f(sum);
    }

    s16x8 eb0 = *(const s16x8*)(qbase + (size_t)(j0 + jh + l15)*32 + kg*8);
    s16x8 eb1 = *(const s16x8*)(qbase + (size_t)(j0 + jh + 16 + l15)*32 + kg*8);
    f4 acc[2][4];
    #pragma unroll
    for(int jb=0;jb<2;jb++)
        #pragma unroll
        for(int jj=0;jj<4;jj++) acc[jb][jj] = (f4){0.f,0.f,0.f,0.f};
    float csp0 = 0.f, csp1 = 0.f;
    const f4 z = {0.f,0.f,0.f,0.f};

    auto stage = [&](int ic, int buf){
        const u16* src = vtb + (size_t)ic*8192 + wv_*1024 + lane*8;
        u16* dst = V + buf*8192 + wv_*1024;
        gload(src, dst);
        gload(src + 512, dst + 512);
    };
    auto eph = [&](int ic, int buf){
        s16x8 ea = *(const s16x8*)(qbase + (size_t)(ic*64 + isub*16 + l15)*32 + kg*8);
        f4 cc = *(const f4*)&CR[ic*64 + isub*16 + kg*4];
        int wbase = buf*4096 + pairOff + ((jcH*2 + (kg>>1))*16 + l15)*8 + (kg&1)*4;
        {
            f4 e = mfma16(ea, eb0, z);
            float q0 = exp2f(fmaf(e[0], L2E, -cc[0]));
            float q1 = exp2f(fmaf(e[1], L2E, -cc[1]));
            float q2 = exp2f(fmaf(e[2], L2E, -cc[2]));
            float q3 = exp2f(fmaf(e[3], L2E, -cc[3]));
            csp0 += q0 + q1 + q2 + q3;
            u32x2 pk = { cvtpk(q0, q1), cvtpk(q2, q3) };
            *(u32x2*)&P[wbase] = pk;
        }
        {
            f4 e = mfma16(ea, eb1, z);
            float q0 = exp2f(fmaf(e[0], L2E, -cc[0]));
            float q1 = exp2f(fmaf(e[1], L2E, -cc[1]));
            float q2 = exp2f(fmaf(e[2], L2E, -cc[2]));
            float q3 = exp2f(fmaf(e[3], L2E, -cc[3]));
            csp1 += q0 + q1 + q2 + q3;
            u32x2 pk = { cvtpk(q0, q1), cvtpk(q2, q3) };
            *(u32x2*)&P[wbase + 512] = pk;
        }
    };

    __syncthreads();                 // CR visible
    stage(0, 0);
    eph(0, 0);
    __syncthreads();
    for(int it=0; it<32; it++){
        int cur = it & 1;
        if(it < 31){ stage(it+1, cur^1); eph(it+1, cur^1); }
        s16x8 pa0 = *(const s16x8*)&P[cur*4096 + pairOff + lane*8];
        s16x8 pa1 = *(const s16x8*)&P[cur*4096 + pairOff + 512 + lane*8];
        __builtin_amdgcn_s_setprio(1);
        #pragma unroll
        for(int jj=0;jj<4;jj++){
            s16x8 vf = *(const s16x8*)&V[cur*8192 + ih*4096 + (jcH*4 + jj)*512 + lane*8];
            acc[0][jj] = mfma16(pa0, vf, acc[0][jj]);
            acc[1][jj] = mfma16(pa1, vf, acc[1][jj]);
        }
        __builtin_amdgcn_s_setprio(0);
        __syncthreads();
    }
    csp0 += __shfl_xor(csp0, 16); csp0 += __shfl_xor(csp0, 32);
    csp1 += __shfl_xor(csp1, 16); csp1 += __shfl_xor(csp1, 32);
    if(lane < 16){
        int g = ih*2 + jcH;
        csl[g*64 + jh + l15]      = csp0;
        csl[g*64 + jh + 16 + l15] = csp1;
    }
    __syncthreads();
    float* comb = (float*)SB;        // (jw*2+jcH)*2048 + (jb*4+jj)*256 + lane*4
    if(ih == 1){
        #pragma unroll
        for(int jb=0;jb<2;jb++)
            #pragma unroll
            for(int jj=0;jj<4;jj++)
                *(f4*)&comb[(jw*2+jcH)*2048 + (jb*4+jj)*256 + lane*4] = acc[jb][jj];
    }
    __syncthreads();
    u16* Td = (u16*)(SB + 32768);
    if(ih == 0){
        #pragma unroll
        for(int jb=0;jb<2;jb++)
            #pragma unroll
            for(int jj=0;jj<4;jj++){
                f4 o = *(const f4*)&comb[(jw*2+jcH)*2048 + (jb*4+jj)*256 + lane*4];
                acc[jb][jj][0] += o[0]; acc[jb][jj][1] += o[1];
                acc[jb][jj][2] += o[2]; acc[jb][jj][3] += o[3];
            }
        #pragma unroll
        for(int jb=0;jb<2;jb++)
            #pragma unroll
            for(int r=0;r<4;r++){
                int jr = jh + jb*16 + kg*4 + r;
                float inv = 1.0f / (1e-9f + csl[jr] + csl[64+jr] + csl[128+jr] + csl[192+jr]);
                int n = j0 + jr;
                const u16* hrow = hprev + (size_t)(b*2048 + n)*ldh;
                #pragma unroll
                for(int jj=0;jj<4;jj++){
                    int c = (jcH*4 + jj)*16 + l15;
                    Td[jr*128 + (c ^ ((jr&7)<<3))] = f2bf(bf2f(hrow[c]) - acc[jb][jj][r]*inv);
                }
            }
    }
    __syncthreads();
    // ---- phase 2: t-proj GEMM over Td ----
    int jw2 = wv_ >> 1, ih2 = wv_ & 1;
    int jh2 = jw2 * 16;
    f4 accT[4];
    #pragma unroll
    for(int j2=0;j2<4;j2++) accT[j2] = (f4){0.f,0.f,0.f,0.f};
    {
        int arow_l = jh2 + l15;
        #pragma unroll
        for(int ks=0; ks<4; ks++){
            s16x8 a = *(const s16x8*)&Td[arow_l*128 + ((ks*32 + kg*8) ^ ((arow_l&7)<<3))];
            #pragma unroll
            for(int j2=0;j2<4;j2++){
                int o = ih2*64 + j2*16 + l15;
                s16x8 bb = *(const s16x8*)(wtb + (size_t)o*128 + ks*32 + kg*8);
                accT[j2] = mfma16(a, bb, accT[j2]);
            }
        }
    }
    u16* T2 = (u16*)SB;
    #pragma unroll
    for(int j2=0;j2<4;j2++){
        int o = ih2*64 + j2*16 + l15;
        float bto = bt[o], gg = sg[o], be = sb[o];
        #pragma unroll
        for(int r=0;r<4;r++){
            int jr = jh2 + kg*4 + r;
            int n = j0 + jr;
            float t = accT[j2][r] + bto;
            float hv = bf2f(hprev[(size_t)(b*2048 + n)*ldh + o]);
            float hn = hv + fmaxf(gg*t + be, 0.f);
            u16 hb = f2bf(hn);
            catb_o[(size_t)(b*2048 + n)*512 + o] = hb;
            T2[jr*128 + (o ^ ((jr&7)<<3))] = hb;
        }
    }
    __syncthreads();
    if(doQV){
        f4 accv[4], accq;
        #pragma unroll
        for(int jj=0;jj<4;jj++) accv[jj] = (f4){0.f,0.f,0.f,0.f};
        accq = (f4){0.f,0.f,0.f,0.f};
        int row = jh2 + l15;
        #pragma unroll
        for(int ks=0; ks<4; ks++){
            s16x8 a = *(const s16x8*)&T2[row*128 + ((ks*32 + kg*8) ^ ((row&7)<<3))];
            #pragma unroll
            for(int jj=0;jj<4;jj++){
                s16x8 bb = *(const s16x8*)(wvb2 + (size_t)((ih2*4+jj)*16 + l15)*128 + ks*32 + kg*8);
                accv[jj] = mfma16(a, bb, accv[jj]);
            }
            s16x8 wf_ = *(const s16x8*)(wqkb2 + (size_t)(ih2*16 + l15)*128 + ks*32 + kg*8);
            accq = mfma16(wf_, a, accq);
        }
        int nb = j0 + jh2;
        int it2 = nb >> 5;
        int k0 = (nb & 31) + kg*4;
        int vbase = ((k0 >> 3)*16)*8 + (k0 & 7);
        #pragma unroll
        for(int jj=0;jj<4;jj++){
            int jc4 = ih2*4 + jj;
            float bvo = bv2[jc4*16 + l15];
            us4 pk;
            #pragma unroll
            for(int r=0;r<4;r++) pk[r] = f2bf(accv[jj][r] + bvo);
            *(us4*)(vt2 + (size_t)((b*64 + it2)*8 + jc4)*512 + vbase + l15*8) = pk;
        }
        int n = j0 + jh2 + l15;
        us4 pk;
        #pragma unroll
        for(int r=0;r<4;r++) pk[r] = f2bf(accq[r]);
        *(us4*)(qb2 + (size_t)(b*2048 + n)*32 + ih2*16 + kg*4) = pk;
    }
}

// ---------------- fuse conv (1024x512) + affine + leaky + partial max ----------------
__global__ __launch_bounds__(512) void k_fuse(const u16* catb, const u16* wft,
                                              const float* fg, const float* fb, float* gpart){
    __shared__ u16 AB[24576];        // A[0,8192) u16, B[8192,24576)
    __shared__ float red[512];
    int bid2 = swz1024(blockIdx.x);
    int b  = bid2 >> 6;
    int rest = bid2 & 63;
    int ng = rest >> 2;
    int og = rest & 3;
    int tid = threadIdx.x;
    int lane = tid & 63, wv_ = tid >> 6;
    int wn = wv_ >> 2, wo = wv_ & 3;
    int l15 = lane & 15, kg = lane >> 4;

    f4 acc[4][4];
    #pragma unroll
    for(int mi=0;mi<4;mi++)
        #pragma unroll
        for(int j=0;j<4;j++) acc[mi][j] = (f4){0.f,0.f,0.f,0.f};

    for(int ksc=0; ksc<8; ksc++){
        if(ksc) __syncthreads();
        #pragma unroll
        for(int q=0;q<2;q++){
            int s = wv_*128 + q*64 + lane;
            int r = s >> 3;
            int c16 = (s & 7) ^ (r & 7);
            const u16* g = catb + (size_t)(b*2048 + ng*128 + r)*512 + ksc*64 + c16*8;
            gload(g, &AB[wv_*1024 + q*512]);
        }
        #pragma unroll
        for(int q=0;q<4;q++){
            int p = wv_*4 + q;
            int jgl = p >> 1, ksl = p & 1;
            const u16* g = wft + (size_t)((og*16 + jgl)*16 + ksc*2 + ksl)*512 + lane*8;
            gload(g, &AB[8192 + p*512]);
        }
        __syncthreads();
        #pragma unroll
        for(int ks=0; ks<2; ks++){
            s16x8 av[4], bw[4];
            #pragma unroll
            for(int mi=0;mi<4;mi++){
                int row = wn*64 + mi*16 + l15;
                av[mi] = *(const s16x8*)&AB[row*64 + ((ks*32 + kg*8) ^ ((row&7)<<3))];
            }
            #pragma unroll
            for(int j=0;j<4;j++){
                int p = (wo*4 + j)*2 + ks;
                bw[j] = *(const s16x8*)&AB[8192 + p*512 + lane*8];
            }
            #pragma unroll
            for(int j=0;j<4;j++)
                #pragma unroll
                for(int mi=0;mi<4;mi++)
                    acc[mi][j] = mfma16(av[mi], bw[j], acc[mi][j]);
        }
    }
    float vmax[4];
    #pragma unroll
    for(int j=0;j<4;j++){
        int o = og*256 + wo*64 + j*16 + l15;
        float fgv = fg[o], fbv = fb[o];
        float vm = -1e30f;
        #pragma unroll
        for(int mi=0;mi<4;mi++)
            #pragma unroll
            for(int r=0;r<4;r++){
                float f = fgv*acc[mi][j][r] + fbv;
                f = (f > 0.f) ? f : 0.2f*f;
                vm = fmaxf(vm, f);
            }
        vm = fmaxf(vm, __shfl_xor(vm, 16));
        vm = fmaxf(vm, __shfl_xor(vm, 32));
        vmax[j] = vm;
    }
    if(lane < 16){
        #pragma unroll
        for(int j=0;j<4;j++) red[(wo*2 + wn)*64 + j*16 + lane] = vmax[j];
    }
    __syncthreads();
    if(tid < 256){
        int wo2 = tid >> 6, ol = tid & 63;
        float m = fmaxf(red[(wo2*2+0)*64 + ol], red[(wo2*2+1)*64 + ol]);
        gpart[(size_t)(ng*16 + b)*1024 + og*256 + wo2*64 + ol] = m;
    }
}

__global__ __launch_bounds__(256) void k_gmax(const float* gpart, float* g){
    int i = blockIdx.x*256 + threadIdx.x;   // 16384
    float m = gpart[i];
    #pragma unroll
    for(int p=1;p<16;p++) m = fmaxf(m, gpart[(size_t)p*16384 + i]);
    g[i] = m;
}

// ---------------- small dense layers: one wave per output ----------------
__global__ __launch_bounds__(256) void k_mlp(const float* in, const float* W, const float* bias,
                                             const float* gm, const float* bt, float* out,
                                             int IN, int OUT, int dorelu){
    int wid = blockIdx.x*4 + (threadIdx.x >> 6);
    int lane = threadIdx.x & 63;
    int b = wid / OUT, o = wid - b*OUT;
    if(b >= 16) return;
    const f4* ir = (const f4*)(in + (size_t)b*IN);
    const f4* wr = (const f4*)(W + (size_t)o*IN);
    float s = 0.f;
    for(int k=lane; k < (IN>>2); k += 64){
        f4 a = ir[k], w = wr[k];
        s += a[0]*w[0] + a[1]*w[1] + a[2]*w[2] + a[3]*w[3];
    }
    #pragma unroll
    for(int d=1; d<64; d<<=1) s += __shfl_xor(s, d);
    if(lane == 0){
        if(bias) s += bias[o];
        if(gm) s = gm[o]*s + bt[o];
        if(dorelu) s = fmaxf(s, 0.f);
        out[(size_t)b*OUT + o] = s;
    }
}

// ---------------- workspace layout (bytes) ----------------
constexpr size_t MB = 1048576;
constexpr size_t OFF_WB   = 0;
constexpr size_t OFF_H1TB = 2*MB;
constexpr size_t OFF_HTB  = 10*MB;          // 8 MB (bf16 h for blk0)
constexpr size_t OFF_QB0  = 26*MB;
constexpr size_t OFF_QB1  = 28*MB;
constexpr size_t OFF_VB0  = 30*MB;
constexpr size_t OFF_VB1  = 38*MB;
constexpr size_t OFF_CROW = 46*MB;              // 512 KB (4 partials)
constexpr size_t OFF_GP   = 46*MB + 524288;     // 1 MB
constexpr size_t OFF_CATB = 112*MB;
constexpr size_t OFF_G    = 144*MB;
constexpr size_t OFF_H1V  = OFF_G + 65536;
constexpr size_t OFF_H2V  = OFF_H1V + 32768;

extern "C" void kernel_launch(void* const* d_in, const int* in_sizes, int n_in,
                              void* d_out, int out_size, void* d_ws, size_t ws_size,
                              hipStream_t stream){
    const float* x       = (const float*)d_in[0];
    const float* conv1_w = (const float*)d_in[1];
    const float* bn1_g   = (const float*)d_in[2];
    const float* bn1_b   = (const float*)d_in[3];
    const float* conv2_w = (const float*)d_in[4];
    const float* bn2_g   = (const float*)d_in[5];
    const float* bn2_b   = (const float*)d_in[6];
    const float* sa_wqk  = (const float*)d_in[7];
    const float* sa_wv   = (const float*)d_in[8];
    const float* sa_bv   = (const float*)d_in[9];
    const float* sa_wt   = (const float*)d_in[10];
    const float* sa_bt   = (const float*)d_in[11];
    const float* sa_g    = (const float*)d_in[12];
    const float* sa_b    = (const float*)d_in[13];
    const float* fuse_w  = (const float*)d_in[14];
    const float* fuse_g  = (const float*)d_in[15];
    const float* fuse_b  = (const float*)d_in[16];
    const float* lin1_w  = (const float*)d_in[17];
    const float* bn6_g   = (const float*)d_in[18];
    const float* bn6_b   = (const float*)d_in[19];
    const float* lin2_w  = (const float*)d_in[20];
    const float* lin2_b  = (const float*)d_in[21];
    const float* bn7_g   = (const float*)d_in[22];
    const float* bn7_b   = (const float*)d_in[23];
    const float* lin3_w  = (const float*)d_in[24];
    const float* lin3_b  = (const float*)d_in[25];

    char* ws = (char*)d_ws;
    u16*   wb    = (u16*)(ws + OFF_WB);
    u16*   h1tb  = (u16*)(ws + OFF_H1TB);
    u16*   htb   = (u16*)(ws + OFF_HTB);
    u16*   qbb[2] = { (u16*)(ws + OFF_QB0), (u16*)(ws + OFF_QB1) };
    u16*   vtb[2] = { (u16*)(ws + OFF_VB0), (u16*)(ws + OFF_VB1) };
    float* crowp = (float*)(ws + OFF_CROW);
    float* gpart = (float*)(ws + OFF_GP);
    u16*   catb  = (u16*)(ws + OFF_CATB);
    float* gbuf  = (float*)(ws + OFF_G);
    float* h1v   = (float*)(ws + OFF_H1V);
    float* h2v   = (float*)(ws + OFF_H2V);

    k_cast <<<2688, 256, 0, stream>>>(conv2_w, sa_wqk, sa_wv, sa_wt, fuse_w, wb);
    k_stem1<<<128,  256, 0, stream>>>(x, conv1_w, bn1_g, bn1_b, h1tb);
    k_conv2qv<<<512, 256, 0, stream>>>(h1tb, wb, bn2_g, bn2_b, htb,
                                       wb + 16384, wb + 32768, sa_bv, qbb[0], vtb[0]);

    for(int blk = 0; blk < 4; blk++){
        int cur = blk & 1, nxt = cur ^ 1;
        const u16* hprev = (blk == 0) ? htb : (catb + (size_t)(blk-1)*128);
        int        ldh   = (blk == 0) ? 128 : 512;
        const u16* wtb  = wb + 98304 + blk*16384;
        int nb2 = (blk < 3) ? (blk + 1) : 3;
        const u16* wqkb2 = wb + 16384 + nb2*4096;
        const u16* wvb2  = wb + 32768 + nb2*16384;

        k_passA<<<2048, 256, 0, stream>>>(qbb[cur], crowp);
        k_passBT<<<512, 512, 0, stream>>>(qbb[cur], vtb[cur], crowp, hprev, ldh,
                                          wtb, sa_bt + blk*128, sa_g + blk*128, sa_b + blk*128,
                                          catb + (size_t)blk*128,
                                          wqkb2, wvb2, sa_bv + nb2*128,
                                          qbb[nxt], vtb[nxt], (blk < 3) ? 1 : 0);
    }

    k_fuse<<<1024, 512, 0, stream>>>(catb, wb + 163840, fuse_g, fuse_b, gpart);
    k_gmax<<<64,   256, 0, stream>>>(gpart, gbuf);
    k_mlp <<<2048, 256, 0, stream>>>(gbuf, lin1_w, nullptr, bn6_g, bn6_b, h1v, 1024, 512, 1);
    k_mlp <<<1024, 256, 0, stream>>>(h1v, lin2_w, lin2_b, bn7_g, bn7_b, h2v, 512, 256, 1);
    k_mlp <<<160,  256, 0, stream>>>(h2v, lin3_w, lin3_b, nullptr, nullptr,
                                     (float*)d_out, 256, 40, 0);
}

// Round 18
// 448.264 us; speedup vs baseline: 1.2395x; 1.2395x over previous
//
#include <hip/hip_runtime.h>

typedef __attribute__((ext_vector_type(4))) float f4;
typedef __attribute__((ext_vector_type(8))) short s16x8;
typedef __attribute__((ext_vector_type(4))) unsigned short us4;
typedef __attribute__((ext_vector_type(2))) unsigned int u32x2;
typedef unsigned short u16;
typedef unsigned int u32;

#define DEVI __device__ __forceinline__

DEVI u16 f2bf(float f){
    u32 u = __builtin_bit_cast(u32, f);
    u32 r = (u + 0x7fffu + ((u >> 16) & 1u)) >> 16;
    return (u16)r;
}
DEVI f4 mfma16(s16x8 a, s16x8 b, f4 c){
    return __builtin_amdgcn_mfma_f32_16x16x32_bf16(a, b, c, 0, 0, 0);
}
DEVI u32 cvtpk(float lo, float hi){
    u32 r;
    asm("v_cvt_pk_bf16_f32 %0, %1, %2" : "=v"(r) : "v"(lo), "v"(hi));
    return r;
}
// async global->LDS, 16B per lane; dst = wave-uniform base + lane*16
DEVI void gload(const u16* g, u16* l){
    __builtin_amdgcn_global_load_lds((const __attribute__((address_space(1))) void*)g,
                                     (__attribute__((address_space(3))) void*)l, 16, 0, 0);
}

#define L2E 1.44269504088896340736f

// ---------------- weight bf16 cast ----------------
__global__ __launch_bounds__(256) void k_cast(const float* w2, const float* wqk,
                                              const float* wv, const float* wt,
                                              const float* wf, u16* out){
    int i = blockIdx.x * 256 + threadIdx.x;
    if(i < 16384)       out[i] = f2bf(w2[i]);
    else if(i < 32768)  out[i] = f2bf(wqk[i - 16384]);
    else if(i < 98304)  out[i] = f2bf(wv[i - 32768]);
    else if(i < 163840) out[i] = f2bf(wt[i - 98304]);
    else if(i < 688128){
        int t = i - 163840;          // t = o*512 + c
        int o = t >> 9, c = t & 511;
        int jg = o >> 4, l15 = o & 15, ks = c >> 5, kr = c & 31;
        out[163840 + (size_t)(jg*16 + ks)*512 + ((kr>>3)*16 + l15)*8 + (kr&7)] = f2bf(wf[t]);
    }
}

// ---------------- stem conv1 (+bn+relu) -> h1 bf16 n-major [b][n][128] ----------------
__global__ __launch_bounds__(256) void k_stem1(const float* x, const float* w1,
                                               const float* g1, const float* b1, u16* h1tb){
    int t = blockIdx.x * 256 + threadIdx.x;      // 16*2048
    int b = t >> 11, n = t & 2047;
    const float* xb = x + (size_t)b * 3 * 2048 + n;
    float x0 = xb[0], x1 = xb[2048], x2 = xb[4096];
    u32* o = (u32*)(h1tb + (size_t)t * 128);
    #pragma unroll 8
    for(int c = 0; c < 128; c += 2){
        float a0 = fmaxf(g1[c]   * (w1[c*3+0]*x0 + w1[c*3+1]*x1 + w1[c*3+2]*x2) + b1[c],   0.f);
        float a1 = fmaxf(g1[c+1] * (w1[c*3+3]*x0 + w1[c*3+4]*x1 + w1[c*3+5]*x2) + b1[c+1], 0.f);
        o[c >> 1] = (u32)f2bf(a0) | ((u32)f2bf(a1) << 16);
    }
}

// XCD swizzle: b -> fixed XCD, consistent across 512- and 1024-grid kernels.
DEVI int swz512(int bid){ return ((bid & 7) << 6) | (bid >> 3); }
DEVI int swz1024(int bid){ return ((bid & 7) << 7) | (bid >> 3); }

// ---------------- shared qv phase (A-tile in swizzled LDS), 4-wave version ----------------
DEVI void qv_phase(const u16* T, const u16* wqkb, const u16* wvb, const float* bv,
                   u16* qb, u16* vt, int b, int n0, int wv_, int l15, int kg){
    f4 accv[8], accq[2];
    #pragma unroll
    for(int j=0;j<8;j++) accv[j] = (f4){0.f,0.f,0.f,0.f};
    accq[0] = (f4){0.f,0.f,0.f,0.f}; accq[1] = accq[0];
    int row = wv_*16 + l15;
    #pragma unroll
    for(int ks=0; ks<4; ks++){
        s16x8 a = *(const s16x8*)&T[row*128 + ((ks*32 + kg*8) ^ ((row&7)<<3))];
        #pragma unroll
        for(int j=0;j<8;j++){
            s16x8 bb = *(const s16x8*)(wvb + (size_t)(j*16 + l15)*128 + ks*32 + kg*8);
            accv[j] = mfma16(a, bb, accv[j]);
        }
        #pragma unroll
        for(int f=0; f<2; f++){
            s16x8 wf_ = *(const s16x8*)(wqkb + (size_t)(f*16 + l15)*128 + ks*32 + kg*8);
            accq[f] = mfma16(wf_, a, accq[f]);
        }
    }
    int nb = n0 + wv_*16;
    int it = nb >> 5;
    int k0 = (nb & 31) + kg*4;
    int vbase = ((k0 >> 3)*16)*8 + (k0 & 7);
    #pragma unroll
    for(int j=0;j<8;j++){
        float bvo = bv[j*16 + l15];
        us4 pk;
        #pragma unroll
        for(int r=0;r<4;r++) pk[r] = f2bf(accv[j][r] + bvo);
        *(us4*)(vt + (size_t)((b*64 + it)*8 + j)*512 + vbase + l15*8) = pk;
    }
    int n = n0 + wv_*16 + l15;
    #pragma unroll
    for(int f=0; f<2; f++){
        us4 pk;
        #pragma unroll
        for(int r=0;r<4;r++) pk[r] = f2bf(accq[f][r]);
        *(us4*)(qb + (size_t)(b*2048 + n)*32 + f*16 + kg*4) = pk;
    }
}

// ---------------- conv2 (+bn+relu) + fused q/v projection (blk0) ----------------
__global__ __launch_bounds__(256) void k_conv2qv(const u16* h1tb, const u16* w2b,
                                                 const float* g2, const float* b2,
                                                 float* ht0,
                                                 const u16* wqkb, const u16* wvb,
                                                 const float* bv, u16* qb, u16* vt){
    __shared__ u16 T[8192];
    int bid2 = swz512(blockIdx.x);
    int b = bid2 >> 5;
    int n0 = (bid2 & 31) << 6;
    int lane = threadIdx.x & 63, wv_ = threadIdx.x >> 6;
    int l15 = lane & 15, kg = lane >> 4;
    const u16* arow = h1tb + (size_t)(b*2048 + n0 + wv_*16 + l15) * 128 + kg*8;
    f4 acc[8];
    #pragma unroll
    for(int j=0;j<8;j++) acc[j] = (f4){0.f,0.f,0.f,0.f};
    #pragma unroll
    for(int ks=0; ks<4; ks++){
        s16x8 a = *(const s16x8*)(arow + ks*32);
        #pragma unroll
        for(int j=0;j<8;j++){
            s16x8 bb = *(const s16x8*)(w2b + (size_t)(j*16 + l15)*128 + ks*32 + kg*8);
            acc[j] = mfma16(a, bb, acc[j]);
        }
    }
    int nn0 = n0 + wv_*16 + kg*4;
    #pragma unroll
    for(int j=0;j<8;j++){
        int o = j*16 + l15;
        float gg = g2[o], be = b2[o];
        #pragma unroll
        for(int r=0;r<4;r++){
            float h = fmaxf(gg * acc[j][r] + be, 0.f);
            int nl = wv_*16 + kg*4 + r;
            ht0[(size_t)(b*2048 + nn0 + r) * 128 + o] = h;
            T[nl*128 + (o ^ ((nl&7)<<3))] = f2bf(h);
        }
    }
    __syncthreads();
    qv_phase(T, wqkb, wvb, bv, qb, vt, b, n0, wv_, l15, kg);
}

// ---------------- pass A (j-split halves): crowp[jh][b][i] = log2(sum_j exp e) ----------------
__global__ __launch_bounds__(256) void k_passA(const u16* qb, float* crowp){
    int bid2 = swz1024(blockIdx.x);
    int b = bid2 >> 6;
    int rest = bid2 & 63;
    int i0 = (rest >> 1) << 6;
    int jh = rest & 1;
    int jbeg = jh << 10;
    int lane = threadIdx.x & 63, wv_ = threadIdx.x >> 6;
    int l15 = lane & 15, kg = lane >> 4;
    const u16* qbase = qb + (size_t)b * 2048 * 32;
    s16x8 af = *(const s16x8*)(qbase + (size_t)(i0 + wv_*16 + l15)*32 + kg*8);
    float m[4], s[4], mml[4];
    const f4 z = {0.f,0.f,0.f,0.f};
    {
        s16x8 b0 = *(const s16x8*)(qbase + (size_t)(jbeg + l15)*32 + kg*8);
        s16x8 b1 = *(const s16x8*)(qbase + (size_t)(jbeg + 16 + l15)*32 + kg*8);
        f4 e0 = mfma16(af, b0, z);
        f4 e1 = mfma16(af, b1, z);
        #pragma unroll
        for(int r=0;r<4;r++){
            m[r] = fmaxf(e0[r], e1[r]);
            mml[r] = -m[r]*L2E;
            s[r] = exp2f(fmaf(e0[r], L2E, mml[r])) + exp2f(fmaf(e1[r], L2E, mml[r]));
        }
    }
    for(int j0=jbeg+32; j0<jbeg+1024; j0+=32){
        s16x8 b0 = *(const s16x8*)(qbase + (size_t)(j0 + l15)*32 + kg*8);
        s16x8 b1 = *(const s16x8*)(qbase + (size_t)(j0 + 16 + l15)*32 + kg*8);
        f4 e0 = mfma16(af, b0, z);
        f4 e1 = mfma16(af, b1, z);
        #pragma unroll
        for(int r=0;r<4;r++){
            float mx = fmaxf(e0[r], e1[r]);
            if(mx > m[r] + 8.f){
                s[r] *= exp2f((m[r]-mx)*L2E);
                m[r] = mx; mml[r] = -mx*L2E;
            }
            s[r] += exp2f(fmaf(e0[r], L2E, mml[r])) + exp2f(fmaf(e1[r], L2E, mml[r]));
        }
    }
    #pragma unroll
    for(int d=1; d<16; d<<=1){
        #pragma unroll
        for(int r=0;r<4;r++){
            float mo = __shfl_xor(m[r], d);
            float so = __shfl_xor(s[r], d);
            float mn = fmaxf(m[r], mo);
            s[r] = s[r]*exp2f((m[r]-mn)*L2E) + so*exp2f((mo-mn)*L2E);
            m[r] = mn;
        }
    }
    if(l15 == 0){
        #pragma unroll
        for(int r=0;r<4;r++){
            int i = i0 + wv_*16 + kg*4 + r;
            crowp[jh*32768 + b*2048 + i] = m[r]*L2E + log2f(s[r]);
        }
    }
}

// ---------------- pass B + tail + next-qv fused (R14/R16 config) ----------------
// Phase 1 roles: 8 waves = (jw 0..1: 32 j) x (ih 0..1: i-half) x (jcH 0..1: c-half).
// Phase 2 roles: (wv>>1: 16 j, wv&1: o-half) reading shared Td.
// LDS: [0,32768) V dbuf | [32768,49152) P dbuf 2x8KB | [49152,57344) CR | [57344,58368) csl[4][64]
__global__ __launch_bounds__(512) void k_passBT(const u16* qb, const u16* vt,
                                                const float* crowp,
                                                const float* hprev, int ldh,
                                                const u16* wtb, const float* bt,
                                                const float* sg, const float* sb,
                                                float* catf_o, u16* catb_o,
                                                const u16* wqkb2, const u16* wvb2,
                                                const float* bv2,
                                                u16* qb2, u16* vt2, int doQV){
    __shared__ __align__(16) char SB[58368];
    u16*   V   = (u16*)SB;
    u16*   P   = (u16*)(SB + 32768);          // P[buf] = P + buf*4096 (u16)
    float* CR  = (float*)(SB + 49152);
    float* csl = (float*)(SB + 57344);        // [g 4][64]
    int bid2 = swz512(blockIdx.x);
    int b = bid2 >> 5;
    int j0 = (bid2 & 31) << 6;
    int tid = threadIdx.x;
    int lane = tid & 63, wv_ = tid >> 6;
    int jw = wv_ >> 2, ih = (wv_ >> 1) & 1, jcH = wv_ & 1;
    int l15 = lane & 15, kg = lane >> 4;
    int jh = jw * 32;
    int pairOff = (jw*2 + ih) * 1024;
    int isub = ih*2 + jcH;
    const u16* qbase = qb + (size_t)b * 2048 * 32;
    const u16* vtb = vt + (size_t)b * 64*8*512;

    #pragma unroll
    for(int p=0;p<4;p++){
        int i = p*512 + tid;
        float c0 = crowp[b*2048 + i], c1 = crowp[32768 + b*2048 + i];
        float mx = fmaxf(c0, c1), mn = fminf(c0, c1);
        CR[i] = mx + log2f(1.f + exp2f(mn - mx));
    }

    s16x8 eb0 = *(const s16x8*)(qbase + (size_t)(j0 + jh + l15)*32 + kg*8);
    s16x8 eb1 = *(const s16x8*)(qbase + (size_t)(j0 + jh + 16 + l15)*32 + kg*8);
    f4 acc[2][4];
    #pragma unroll
    for(int jb=0;jb<2;jb++)
        #pragma unroll
        for(int jj=0;jj<4;jj++) acc[jb][jj] = (f4){0.f,0.f,0.f,0.f};
    float csp0 = 0.f, csp1 = 0.f;
    const f4 z = {0.f,0.f,0.f,0.f};

    auto stage = [&](int ic, int buf){
        const u16* src = vtb + (size_t)ic*8192 + wv_*1024 + lane*8;
        u16* dst = V + buf*8192 + wv_*1024;
        gload(src, dst);
        gload(src + 512, dst + 512);
    };
    auto eph = [&](int ic, int buf){
        s16x8 ea = *(const s16x8*)(qbase + (size_t)(ic*64 + isub*16 + l15)*32 + kg*8);
        f4 cc = *(const f4*)&CR[ic*64 + isub*16 + kg*4];
        int wbase = buf*4096 + pairOff + ((jcH*2 + (kg>>1))*16 + l15)*8 + (kg&1)*4;
        {
            f4 e = mfma16(ea, eb0, z);
            float q0 = exp2f(fmaf(e[0], L2E, -cc[0]));
            float q1 = exp2f(fmaf(e[1], L2E, -cc[1]));
            float q2 = exp2f(fmaf(e[2], L2E, -cc[2]));
            float q3 = exp2f(fmaf(e[3], L2E, -cc[3]));
            csp0 += q0 + q1 + q2 + q3;
            u32x2 pk = { cvtpk(q0, q1), cvtpk(q2, q3) };
            *(u32x2*)&P[wbase] = pk;
        }
        {
            f4 e = mfma16(ea, eb1, z);
            float q0 = exp2f(fmaf(e[0], L2E, -cc[0]));
            float q1 = exp2f(fmaf(e[1], L2E, -cc[1]));
            float q2 = exp2f(fmaf(e[2], L2E, -cc[2]));
            float q3 = exp2f(fmaf(e[3], L2E, -cc[3]));
            csp1 += q0 + q1 + q2 + q3;
            u32x2 pk = { cvtpk(q0, q1), cvtpk(q2, q3) };
            *(u32x2*)&P[wbase + 512] = pk;
        }
    };

    __syncthreads();                 // CR visible
    stage(0, 0);
    eph(0, 0);
    __syncthreads();
    for(int it=0; it<32; it++){
        int cur = it & 1;
        if(it < 31){ stage(it+1, cur^1); eph(it+1, cur^1); }
        s16x8 pa0 = *(const s16x8*)&P[cur*4096 + pairOff + lane*8];
        s16x8 pa1 = *(const s16x8*)&P[cur*4096 + pairOff + 512 + lane*8];
        __builtin_amdgcn_s_setprio(1);
        #pragma unroll
        for(int jj=0;jj<4;jj++){
            s16x8 vf = *(const s16x8*)&V[cur*8192 + ih*4096 + (jcH*4 + jj)*512 + lane*8];
            acc[0][jj] = mfma16(pa0, vf, acc[0][jj]);
            acc[1][jj] = mfma16(pa1, vf, acc[1][jj]);
        }
        __builtin_amdgcn_s_setprio(0);
        __syncthreads();
    }
    csp0 += __shfl_xor(csp0, 16); csp0 += __shfl_xor(csp0, 32);
    csp1 += __shfl_xor(csp1, 16); csp1 += __shfl_xor(csp1, 32);
    if(lane < 16){
        int g = ih*2 + jcH;
        csl[g*64 + jh + l15]      = csp0;
        csl[g*64 + jh + 16 + l15] = csp1;
    }
    __syncthreads();
    float* comb = (float*)SB;        // (jw*2+jcH)*2048 + (jb*4+jj)*256 + lane*4
    if(ih == 1){
        #pragma unroll
        for(int jb=0;jb<2;jb++)
            #pragma unroll
            for(int jj=0;jj<4;jj++)
                *(f4*)&comb[(jw*2+jcH)*2048 + (jb*4+jj)*256 + lane*4] = acc[jb][jj];
    }
    __syncthreads();
    u16* Td = (u16*)(SB + 32768);
    if(ih == 0){
        #pragma unroll
        for(int jb=0;jb<2;jb++)
            #pragma unroll
            for(int jj=0;jj<4;jj++){
                f4 o = *(const f4*)&comb[(jw*2+jcH)*2048 + (jb*4+jj)*256 + lane*4];
                acc[jb][jj][0] += o[0]; acc[jb][jj][1] += o[1];
                acc[jb][jj][2] += o[2]; acc[jb][jj][3] += o[3];
            }
        #pragma unroll
        for(int jb=0;jb<2;jb++)
            #pragma unroll
            for(int r=0;r<4;r++){
                int jr = jh + jb*16 + kg*4 + r;
                float inv = 1.0f / (1e-9f + csl[jr] + csl[64+jr] + csl[128+jr] + csl[192+jr]);
                int n = j0 + jr;
                const float* hrow = hprev + (size_t)(b*2048 + n)*ldh;
                #pragma unroll
                for(int jj=0;jj<4;jj++){
                    int c = (jcH*4 + jj)*16 + l15;
                    Td[jr*128 + (c ^ ((jr&7)<<3))] = f2bf(hrow[c] - acc[jb][jj][r]*inv);
                }
            }
    }
    __syncthreads();
    // ---- phase 2: t-proj GEMM over Td ----
    int jw2 = wv_ >> 1, ih2 = wv_ & 1;
    int jh2 = jw2 * 16;
    f4 accT[4];
    #pragma unroll
    for(int j2=0;j2<4;j2++) accT[j2] = (f4){0.f,0.f,0.f,0.f};
    {
        int arow_l = jh2 + l15;
        #pragma unroll
        for(int ks=0; ks<4; ks++){
            s16x8 a = *(const s16x8*)&Td[arow_l*128 + ((ks*32 + kg*8) ^ ((arow_l&7)<<3))];
            #pragma unroll
            for(int j2=0;j2<4;j2++){
                int o = ih2*64 + j2*16 + l15;
                s16x8 bb = *(const s16x8*)(wtb + (size_t)o*128 + ks*32 + kg*8);
                accT[j2] = mfma16(a, bb, accT[j2]);
            }
        }
    }
    u16* T2 = (u16*)SB;
    #pragma unroll
    for(int j2=0;j2<4;j2++){
        int o = ih2*64 + j2*16 + l15;
        float bto = bt[o], gg = sg[o], be = sb[o];
        #pragma unroll
        for(int r=0;r<4;r++){
            int jr = jh2 + kg*4 + r;
            int n = j0 + jr;
            float t = accT[j2][r] + bto;
            float hv = hprev[(size_t)(b*2048 + n)*ldh + o];
            float hn = hv + fmaxf(gg*t + be, 0.f);
            size_t oi = (size_t)(b*2048 + n)*512 + o;
            u16 hb = f2bf(hn);
            catf_o[oi] = hn;
            catb_o[oi] = hb;
            T2[jr*128 + (o ^ ((jr&7)<<3))] = hb;
        }
    }
    __syncthreads();
    if(doQV){
        f4 accv[4], accq;
        #pragma unroll
        for(int jj=0;jj<4;jj++) accv[jj] = (f4){0.f,0.f,0.f,0.f};
        accq = (f4){0.f,0.f,0.f,0.f};
        int row = jh2 + l15;
        #pragma unroll
        for(int ks=0; ks<4; ks++){
            s16x8 a = *(const s16x8*)&T2[row*128 + ((ks*32 + kg*8) ^ ((row&7)<<3))];
            #pragma unroll
            for(int jj=0;jj<4;jj++){
                s16x8 bb = *(const s16x8*)(wvb2 + (size_t)((ih2*4+jj)*16 + l15)*128 + ks*32 + kg*8);
                accv[jj] = mfma16(a, bb, accv[jj]);
            }
            s16x8 wf_ = *(const s16x8*)(wqkb2 + (size_t)(ih2*16 + l15)*128 + ks*32 + kg*8);
            accq = mfma16(wf_, a, accq);
        }
        int nb = j0 + jh2;
        int it2 = nb >> 5;
        int k0 = (nb & 31) + kg*4;
        int vbase = ((k0 >> 3)*16)*8 + (k0 & 7);
        #pragma unroll
        for(int jj=0;jj<4;jj++){
            int jc4 = ih2*4 + jj;
            float bvo = bv2[jc4*16 + l15];
            us4 pk;
            #pragma unroll
            for(int r=0;r<4;r++) pk[r] = f2bf(accv[jj][r] + bvo);
            *(us4*)(vt2 + (size_t)((b*64 + it2)*8 + jc4)*512 + vbase + l15*8) = pk;
        }
        int n = j0 + jh2 + l15;
        us4 pk;
        #pragma unroll
        for(int r=0;r<4;r++) pk[r] = f2bf(accq[r]);
        *(us4*)(qb2 + (size_t)(b*2048 + n)*32 + ih2*16 + kg*4) = pk;
    }
}

// ---------------- fuse conv (1024x512) + affine + leaky + partial max ----------------
__global__ __launch_bounds__(512) void k_fuse(const u16* catb, const u16* wft,
                                              const float* fg, const float* fb, float* gpart){
    __shared__ u16 AB[24576];        // A[0,8192) u16, B[8192,24576)
    __shared__ float red[512];
    int bid2 = swz1024(blockIdx.x);
    int b  = bid2 >> 6;
    int rest = bid2 & 63;
    int ng = rest >> 2;
    int og = rest & 3;
    int tid = threadIdx.x;
    int lane = tid & 63, wv_ = tid >> 6;
    int wn = wv_ >> 2, wo = wv_ & 3;
    int l15 = lane & 15, kg = lane >> 4;

    f4 acc[4][4];
    #pragma unroll
    for(int mi=0;mi<4;mi++)
        #pragma unroll
        for(int j=0;j<4;j++) acc[mi][j] = (f4){0.f,0.f,0.f,0.f};

    for(int ksc=0; ksc<8; ksc++){
        if(ksc) __syncthreads();
        #pragma unroll
        for(int q=0;q<2;q++){
            int s = wv_*128 + q*64 + lane;
            int r = s >> 3;
            int c16 = (s & 7) ^ (r & 7);
            const u16* g = catb + (size_t)(b*2048 + ng*128 + r)*512 + ksc*64 + c16*8;
            gload(g, &AB[wv_*1024 + q*512]);
        }
        #pragma unroll
        for(int q=0;q<4;q++){
            int p = wv_*4 + q;
            int jgl = p >> 1, ksl = p & 1;
            const u16* g = wft + (size_t)((og*16 + jgl)*16 + ksc*2 + ksl)*512 + lane*8;
            gload(g, &AB[8192 + p*512]);
        }
        __syncthreads();
        #pragma unroll
        for(int ks=0; ks<2; ks++){
            s16x8 av[4], bw[4];
            #pragma unroll
            for(int mi=0;mi<4;mi++){
                int row = wn*64 + mi*16 + l15;
                av[mi] = *(const s16x8*)&AB[row*64 + ((ks*32 + kg*8) ^ ((row&7)<<3))];
            }
            #pragma unroll
            for(int j=0;j<4;j++){
                int p = (wo*4 + j)*2 + ks;
                bw[j] = *(const s16x8*)&AB[8192 + p*512 + lane*8];
            }
            #pragma unroll
            for(int j=0;j<4;j++)
                #pragma unroll
                for(int mi=0;mi<4;mi++)
                    acc[mi][j] = mfma16(av[mi], bw[j], acc[mi][j]);
        }
    }
    float vmax[4];
    #pragma unroll
    for(int j=0;j<4;j++){
        int o = og*256 + wo*64 + j*16 + l15;
        float fgv = fg[o], fbv = fb[o];
        float vm = -1e30f;
        #pragma unroll
        for(int mi=0;mi<4;mi++)
            #pragma unroll
            for(int r=0;r<4;r++){
                float f = fgv*acc[mi][j][r] + fbv;
                f = (f > 0.f) ? f : 0.2f*f;
                vm = fmaxf(vm, f);
            }
        vm = fmaxf(vm, __shfl_xor(vm, 16));
        vm = fmaxf(vm, __shfl_xor(vm, 32));
        vmax[j] = vm;
    }
    if(lane < 16){
        #pragma unroll
        for(int j=0;j<4;j++) red[(wo*2 + wn)*64 + j*16 + lane] = vmax[j];
    }
    __syncthreads();
    if(tid < 256){
        int wo2 = tid >> 6, ol = tid & 63;
        float m = fmaxf(red[(wo2*2+0)*64 + ol], red[(wo2*2+1)*64 + ol]);
        gpart[(size_t)(ng*16 + b)*1024 + og*256 + wo2*64 + ol] = m;
    }
}

__global__ __launch_bounds__(256) void k_gmax(const float* gpart, float* g){
    int i = blockIdx.x*256 + threadIdx.x;   // 16384
    float m = gpart[i];
    #pragma unroll
    for(int p=1;p<16;p++) m = fmaxf(m, gpart[(size_t)p*16384 + i]);
    g[i] = m;
}

// ---------------- small dense layers: one wave per output ----------------
__global__ __launch_bounds__(256) void k_mlp(const float* in, const float* W, const float* bias,
                                             const float* gm, const float* bt, float* out,
                                             int IN, int OUT, int dorelu){
    int wid = blockIdx.x*4 + (threadIdx.x >> 6);
    int lane = threadIdx.x & 63;
    int b = wid / OUT, o = wid - b*OUT;
    if(b >= 16) return;
    const f4* ir = (const f4*)(in + (size_t)b*IN);
    const f4* wr = (const f4*)(W + (size_t)o*IN);
    float s = 0.f;
    for(int k=lane; k < (IN>>2); k += 64){
        f4 a = ir[k], w = wr[k];
        s += a[0]*w[0] + a[1]*w[1] + a[2]*w[2] + a[3]*w[3];
    }
    #pragma unroll
    for(int d=1; d<64; d<<=1) s += __shfl_xor(s, d);
    if(lane == 0){
        if(bias) s += bias[o];
        if(gm) s = gm[o]*s + bt[o];
        if(dorelu) s = fmaxf(s, 0.f);
        out[(size_t)b*OUT + o] = s;
    }
}

// ---------------- workspace layout (bytes) ----------------
constexpr size_t MB = 1048576;
constexpr size_t OFF_WB   = 0;
constexpr size_t OFF_H1TB = 2*MB;
constexpr size_t OFF_HT0  = 10*MB;
constexpr size_t OFF_QB0  = 26*MB;
constexpr size_t OFF_QB1  = 28*MB;
constexpr size_t OFF_VB0  = 30*MB;
constexpr size_t OFF_VB1  = 38*MB;
constexpr size_t OFF_CROW = 46*MB;
constexpr size_t OFF_GP   = 46*MB + 262144;
constexpr size_t OFF_CATF = 48*MB;
constexpr size_t OFF_CATB = 112*MB;
constexpr size_t OFF_G    = 144*MB;
constexpr size_t OFF_H1V  = OFF_G + 65536;
constexpr size_t OFF_H2V  = OFF_H1V + 32768;

extern "C" void kernel_launch(void* const* d_in, const int* in_sizes, int n_in,
                              void* d_out, int out_size, void* d_ws, size_t ws_size,
                              hipStream_t stream){
    const float* x       = (const float*)d_in[0];
    const float* conv1_w = (const float*)d_in[1];
    const float* bn1_g   = (const float*)d_in[2];
    const float* bn1_b   = (const float*)d_in[3];
    const float* conv2_w = (const float*)d_in[4];
    const float* bn2_g   = (const float*)d_in[5];
    const float* bn2_b   = (const float*)d_in[6];
    const float* sa_wqk  = (const float*)d_in[7];
    const float* sa_wv   = (const float*)d_in[8];
    const float* sa_bv   = (const float*)d_in[9];
    const float* sa_wt   = (const float*)d_in[10];
    const float* sa_bt   = (const float*)d_in[11];
    const float* sa_g    = (const float*)d_in[12];
    const float* sa_b    = (const float*)d_in[13];
    const float* fuse_w  = (const float*)d_in[14];
    const float* fuse_g  = (const float*)d_in[15];
    const float* fuse_b  = (const float*)d_in[16];
    const float* lin1_w  = (const float*)d_in[17];
    const float* bn6_g   = (const float*)d_in[18];
    const float* bn6_b   = (const float*)d_in[19];
    const float* lin2_w  = (const float*)d_in[20];
    const float* lin2_b  = (const float*)d_in[21];
    const float* bn7_g   = (const float*)d_in[22];
    const float* bn7_b   = (const float*)d_in[23];
    const float* lin3_w  = (const float*)d_in[24];
    const float* lin3_b  = (const float*)d_in[25];

    char* ws = (char*)d_ws;
    u16*   wb    = (u16*)(ws + OFF_WB);
    u16*   h1tb  = (u16*)(ws + OFF_H1TB);
    float* ht0   = (float*)(ws + OFF_HT0);
    u16*   qbb[2] = { (u16*)(ws + OFF_QB0), (u16*)(ws + OFF_QB1) };
    u16*   vtb[2] = { (u16*)(ws + OFF_VB0), (u16*)(ws + OFF_VB1) };
    float* crowp = (float*)(ws + OFF_CROW);
    float* gpart = (float*)(ws + OFF_GP);
    float* catf  = (float*)(ws + OFF_CATF);
    u16*   catb  = (u16*)(ws + OFF_CATB);
    float* gbuf  = (float*)(ws + OFF_G);
    float* h1v   = (float*)(ws + OFF_H1V);
    float* h2v   = (float*)(ws + OFF_H2V);

    k_cast <<<2688, 256, 0, stream>>>(conv2_w, sa_wqk, sa_wv, sa_wt, fuse_w, wb);
    k_stem1<<<128,  256, 0, stream>>>(x, conv1_w, bn1_g, bn1_b, h1tb);
    k_conv2qv<<<512, 256, 0, stream>>>(h1tb, wb, bn2_g, bn2_b, ht0,
                                       wb + 16384, wb + 32768, sa_bv, qbb[0], vtb[0]);

    for(int blk = 0; blk < 4; blk++){
        int cur = blk & 1, nxt = cur ^ 1;
        const float* hprev = (blk == 0) ? ht0 : (catf + (size_t)(blk-1)*128);
        int          ldh   = (blk == 0) ? 128 : 512;
        const u16* wtb  = wb + 98304 + blk*16384;
        int nb2 = (blk < 3) ? (blk + 1) : 3;
        const u16* wqkb2 = wb + 16384 + nb2*4096;
        const u16* wvb2  = wb + 32768 + nb2*16384;

        k_passA<<<1024, 256, 0, stream>>>(qbb[cur], crowp);
        k_passBT<<<512, 512, 0, stream>>>(qbb[cur], vtb[cur], crowp, hprev, ldh,
                                          wtb, sa_bt + blk*128, sa_g + blk*128, sa_b + blk*128,
                                          catf + (size_t)blk*128, catb + (size_t)blk*128,
                                          wqkb2, wvb2, sa_bv + nb2*128,
                                          qbb[nxt], vtb[nxt], (blk < 3) ? 1 : 0);
    }

    k_fuse<<<1024, 512, 0, stream>>>(catb, wb + 163840, fuse_g, fuse_b, gpart);
    k_gmax<<<64,   256, 0, stream>>>(gpart, gbuf);
    k_mlp <<<2048, 256, 0, stream>>>(gbuf, lin1_w, nullptr, bn6_g, bn6_b, h1v, 1024, 512, 1);
    k_mlp <<<1024, 256, 0, stream>>>(h1v, lin2_w, lin2_b, bn7_g, bn7_b, h2v, 512, 256, 1);
    k_mlp <<<160,  256, 0, stream>>>(h2v, lin3_w, lin3_b, nullptr, nullptr,
                                     (float*)d_out, 256, 40, 0);
}